// Round 11
// baseline (592.601 us; speedup 1.0000x reference)
//
#include <hip/hip_runtime.h>
#include <math.h>

#define NMOL 512
#define NATOM 64
#define NFLAT (NMOL*NATOM)
#define AEVL 384
#define FK 448           // fp16 feature row: 384 aev | 32 qraev | q | esp | 30 pad(0)
#define D0 256
#define D1 192
#define D2 160
#define MPAD 33024

typedef _Float16 h8 __attribute__((ext_vector_type(8)));
typedef float    f4 __attribute__((ext_vector_type(4)));

#define BSOFF(j) ((((j)>>2)*36) + (((j)&3)*8))

__constant__ float c_sigma[8] = {0.5515909f,1.8886297f,1.3225029f,1.2316629f,
                                 2.1884933f,1.7750372f,1.3677907f,1.3820058f};

__device__ __forceinline__ float wsum(float v){
  #pragma unroll
  for (int o=1;o<64;o<<=1) v += __shfl_xor(v,o);
  return v;
}

// ---------------- AEV -> fp16 feature rows (tail 384..447 zeroed) ----------------
__global__ void cvt_aev_kernel(const float* __restrict__ aev, _Float16* __restrict__ feat){
  int atom = blockIdx.x*4 + (threadIdx.x>>6);
  int c = threadIdx.x & 63;
  if (c >= 56) return;
  int k8 = c*8;
  h8 o;
  if (k8 < AEVL){
    const f4* s = reinterpret_cast<const f4*>(aev + (size_t)atom*AEVL + k8);
    f4 a = s[0], b = s[1];
    o[0]=(_Float16)a[0]; o[1]=(_Float16)a[1]; o[2]=(_Float16)a[2]; o[3]=(_Float16)a[3];
    o[4]=(_Float16)b[0]; o[5]=(_Float16)b[1]; o[6]=(_Float16)b[2]; o[7]=(_Float16)b[3];
  } else {
    #pragma unroll
    for (int i=0;i<8;i++) o[i] = (_Float16)0.f;
  }
  *reinterpret_cast<h8*>(feat + (size_t)atom*FK + k8) = o;
}

// ---- W [4][K][N] f32 -> Wt [4][KT][N][32] fp16 (k-step tiles contiguous, zero-padded) ----
__global__ void wtrans_kernel(const float* __restrict__ W, _Float16* __restrict__ Wt,
                              int K, int N, int KT){
  int pair = blockIdx.x*256 + threadIdx.x;
  if (pair >= N*KT) return;
  int col = pair % N;
  int kb  = pair / N;
  int s = blockIdx.y;
  h8 o[4];
  #pragma unroll
  for (int g=0; g<4; ++g){
    #pragma unroll
    for (int e=0; e<8; ++e){
      int gk = kb*32 + g*8 + e;
      float v = (gk < K) ? W[((size_t)s*K + gk)*N + col] : 0.f;
      o[g][e] = (_Float16)v;
    }
  }
  _Float16* dst = Wt + (((size_t)s*KT + kb)*N + col)*32;
  #pragma unroll
  for (int g=0; g<4; ++g) *reinterpret_cast<h8*>(dst + g*8) = o[g];
}

// ---------------- distances + per-atom species data + per-molecule histogram ----------------
__global__ void prep_kernel(const int* __restrict__ species,
                            const float* __restrict__ coord,
                            float* __restrict__ dbuf, float* __restrict__ sig,
                            float* __restrict__ invj, float* __restrict__ pmf,
                            int* __restrict__ blkhist){
  int m = blockIdx.x, t = threadIdx.x;
  __shared__ float c[192];
  if (t < 192) c[t] = coord[m*192 + t];
  __syncthreads();
  #pragma unroll
  for (int k=0;k<16;k++){
    int p = t + 256*k;
    int i = p >> 6, j = p & 63;
    float dx=c[i*3]-c[j*3], dy=c[i*3+1]-c[j*3+1], dz=c[i*3+2]-c[j*3+2];
    dbuf[m*4096 + p] = sqrtf(dx*dx+dy*dy+dz*dz + 1e-16f) / 0.529177249f;
  }
  if (t < 64){
    int g = m*64+t;
    int s = species[g];
    float sg = c_sigma[s < 0 ? 7 : s];
    sig[g]  = sg;
    invj[g] = 1.7724539f * sg;   // sqrt(pi) fp32
    pmf[g]  = (s>=0) ? 1.f : 0.f;
    #pragma unroll
    for (int sp=0;sp<4;sp++){
      unsigned long long mask = __ballot(s==sp);
      if (t==0) blkhist[m*4+sp] = __popcll(mask);
    }
  }
}

// ---------------- plan: 32-row tiles ----------------
// meta: [0..3] counts, [4..8] base(32-aligned, [8]=total rows), [9..13] tile_base ([13]=total tiles)
__global__ void plan_kernel(const int* __restrict__ blkhist, int* __restrict__ meta,
                            int* __restrict__ blkoff){
  __shared__ int tot[4], base[4];
  int t = threadIdx.x;
  if (t < 4){
    int sum = 0;
    for (int m=0;m<NMOL;m++) sum += blkhist[m*4+t];
    tot[t] = sum;
  }
  __syncthreads();
  if (t == 0){
    int b=0, tb=0;
    meta[4]=0; meta[9]=0;
    for (int s=0;s<4;s++){
      meta[s] = tot[s];
      base[s] = b;
      int tiles = (tot[s]+31)>>5;
      b  += tiles<<5;  tb += tiles;
      meta[5+s]  = b;  meta[10+s] = tb;
    }
  }
  __syncthreads();
  if (t < 4){
    int run = base[t];
    for (int m=0;m<NMOL;m++){ blkoff[m*4+t] = run; run += blkhist[m*4+t]; }
  }
}

// ---------------- deterministic atomic-free scatter ----------------
__global__ void scatter_kernel(const int* __restrict__ species,
                               const int* __restrict__ blkoff,
                               int* __restrict__ idxarr){
  int m = blockIdx.x, a = threadIdx.x, g = m*64+a;
  int s = species[g];
  unsigned long long below = (1ull<<a) - 1ull;
  #pragma unroll
  for (int sp=0;sp<4;sp++){
    unsigned long long mask = __ballot(s==sp);
    if (s==sp){
      int rank = __popcll(mask & below);
      idxarr[blkoff[m*4+sp] + rank] = g;
    }
  }
}

// ================= fused MLP: feat -> h0 -> h1 -> h2 -> scalar, one block = 32 rows =================
// 4 waves: wave w -> rows [rh*16,+16), cols half ch  (rh=w&1, ch=w>>1).
// B k-tiles LDS-staged dbuf (round-10 pattern); h0/h1/h2 LDS-resident, 16B-chunk XOR swizzle.
__global__ __launch_bounds__(256)
void mlp_fused(const _Float16* __restrict__ feat,
               const int* __restrict__ idxarr,
               const int* __restrict__ meta,
               const _Float16* __restrict__ Wt0,   // [4][14][256][32]
               const _Float16* __restrict__ Wt1,   // [4][8][192][32]
               const _Float16* __restrict__ Wt2,   // [4][6][160][32]
               const float* __restrict__ B0, const float* __restrict__ B1,
               const float* __restrict__ B2,
               const float* __restrict__ W3,       // [4][160]
               const float* __restrict__ b3,       // [4]
               float* __restrict__ outv){
  int t = blockIdx.x;
  if (t >= meta[13]) return;
  int s = 0;
  while (s < 3 && t >= meta[10+s]) s++;
  int trow = t - meta[9+s];
  int row0 = meta[4+s] + (trow<<5);
  int mrem = meta[s] - (trow<<5); if (mrem > 32) mrem = 32;

  __shared__ _Float16 Bs[2][256][36];   // 36864 B
  __shared__ _Float16 h0l[32][256];     // 16384 B (h2 aliases)
  __shared__ _Float16 h1l[32][192];     // 12288 B

  int tid = threadIdx.x;
  int w = tid>>6, l = tid&63, lr16 = l&15, lg = l>>4;
  int rh = w&1, ch = w>>1;

  int arow = row0 + rh*16 + lr16;
  int amax = row0 + mrem - 1;
  if (arow > amax) arow = amax;          // clamp (outputs masked)
  const _Float16* ap = feat + (size_t)idxarr[arow]*FK + lg*8;

  int rA = rh*16 + lr16;                 // A-read row for L1/L2
  int rW = rh*16 + lg*4;                 // output row base for epilogues

  // ---------------- L0: 448 -> 256 ----------------
  {
    const _Float16* Wb = Wt0 + (size_t)s*14*256*32;
    f4 acc[8];
    #pragma unroll
    for (int c=0;c<8;c++){ acc[c][0]=0.f;acc[c][1]=0.f;acc[c][2]=0.f;acc[c][3]=0.f; }
    h8 r0 = *(const h8*)(Wb + (size_t)tid*8);
    h8 r1 = *(const h8*)(Wb + (size_t)(tid+256)*8);
    h8 r2 = *(const h8*)(Wb + (size_t)(tid+512)*8);
    h8 r3 = *(const h8*)(Wb + (size_t)(tid+768)*8);
    h8 aR = *(const h8*)ap;
    _Float16* b0p = &Bs[0][0][0];
    *(h8*)(b0p + BSOFF(tid))     = r0;
    *(h8*)(b0p + BSOFF(tid+256)) = r1;
    *(h8*)(b0p + BSOFF(tid+512)) = r2;
    *(h8*)(b0p + BSOFF(tid+768)) = r3;
    __syncthreads();
    int cur = 0;
    for (int kt=0; kt<14; ++kt){
      h8 a = aR;
      if (kt < 13){
        const _Float16* src = Wb + (size_t)(kt+1)*256*32;
        r0 = *(const h8*)(src + (size_t)tid*8);
        r1 = *(const h8*)(src + (size_t)(tid+256)*8);
        r2 = *(const h8*)(src + (size_t)(tid+512)*8);
        r3 = *(const h8*)(src + (size_t)(tid+768)*8);
        aR = *(const h8*)(ap + (kt+1)*32);
      }
      const _Float16* bb = &Bs[cur][0][0];
      #pragma unroll
      for (int c=0;c<8;c++){
        h8 bf = *(const h8*)(bb + (ch*128 + c*16 + lr16)*36 + lg*8);
        acc[c] = __builtin_amdgcn_mfma_f32_16x16x32_f16(a, bf, acc[c], 0, 0, 0);
      }
      if (kt < 13){
        _Float16* bn = &Bs[cur^1][0][0];
        *(h8*)(bn + BSOFF(tid))     = r0;
        *(h8*)(bn + BSOFF(tid+256)) = r1;
        *(h8*)(bn + BSOFF(tid+512)) = r2;
        *(h8*)(bn + BSOFF(tid+768)) = r3;
        __syncthreads();
        cur ^= 1;
      }
    }
    const float* bias = B0 + s*256;
    #pragma unroll
    for (int c=0;c<8;c++){
      int col = ch*128 + c*16 + lr16;
      float bv = bias[col];
      #pragma unroll
      for (int rr=0;rr<4;rr++){
        int r = rW + rr;
        float v = acc[c][rr] + bv;
        v = v > 0.f ? v : 0.1f*expm1f(v*10.f);
        int pc = (((col>>3) ^ (r&7))<<3) | (col&7);
        h0l[r][pc] = (_Float16)v;
      }
    }
  }
  // ---------------- L1: 256 -> 192 ----------------
  {
    const _Float16* Wb = Wt1 + (size_t)s*8*192*32;
    f4 acc[6];
    #pragma unroll
    for (int c=0;c<6;c++){ acc[c][0]=0.f;acc[c][1]=0.f;acc[c][2]=0.f;acc[c][3]=0.f; }
    h8 r0 = *(const h8*)(Wb + (size_t)tid*8);
    h8 r1 = *(const h8*)(Wb + (size_t)(tid+256)*8);
    h8 r2 = *(const h8*)(Wb + (size_t)(tid+512)*8);
    __syncthreads();                        // h0 writes + last L0 Bs reads done
    _Float16* b0p = &Bs[0][0][0];
    *(h8*)(b0p + BSOFF(tid))     = r0;
    *(h8*)(b0p + BSOFF(tid+256)) = r1;
    *(h8*)(b0p + BSOFF(tid+512)) = r2;
    __syncthreads();
    int cur = 0;
    int xr = rA & 7;
    for (int kt=0; kt<8; ++kt){
      h8 a = *(const h8*)(&h0l[rA][0] + (((kt*4 + lg) ^ xr)<<3));
      if (kt < 7){
        const _Float16* src = Wb + (size_t)(kt+1)*192*32;
        r0 = *(const h8*)(src + (size_t)tid*8);
        r1 = *(const h8*)(src + (size_t)(tid+256)*8);
        r2 = *(const h8*)(src + (size_t)(tid+512)*8);
      }
      const _Float16* bb = &Bs[cur][0][0];
      #pragma unroll
      for (int c=0;c<6;c++){
        h8 bf = *(const h8*)(bb + (ch*96 + c*16 + lr16)*36 + lg*8);
        acc[c] = __builtin_amdgcn_mfma_f32_16x16x32_f16(a, bf, acc[c], 0, 0, 0);
      }
      if (kt < 7){
        _Float16* bn = &Bs[cur^1][0][0];
        *(h8*)(bn + BSOFF(tid))     = r0;
        *(h8*)(bn + BSOFF(tid+256)) = r1;
        *(h8*)(bn + BSOFF(tid+512)) = r2;
        __syncthreads();
        cur ^= 1;
      }
    }
    const float* bias = B1 + s*192;
    #pragma unroll
    for (int c=0;c<6;c++){
      int col = ch*96 + c*16 + lr16;
      float bv = bias[col];
      #pragma unroll
      for (int rr=0;rr<4;rr++){
        int r = rW + rr;
        float v = acc[c][rr] + bv;
        v = v > 0.f ? v : 0.1f*expm1f(v*10.f);
        int pc = (((col>>3) ^ (r&7))<<3) | (col&7);
        h1l[r][pc] = (_Float16)v;
      }
    }
  }
  // ---------------- L2: 192 -> 160 (h2 aliases h0l, pitch 256) ----------------
  _Float16* h2l = &h0l[0][0];
  {
    const _Float16* Wb = Wt2 + (size_t)s*6*160*32;
    f4 acc[5];
    #pragma unroll
    for (int c=0;c<5;c++){ acc[c][0]=0.f;acc[c][1]=0.f;acc[c][2]=0.f;acc[c][3]=0.f; }
    h8 r0 = *(const h8*)(Wb + (size_t)tid*8);
    h8 r1 = *(const h8*)(Wb + (size_t)(tid+256)*8);
    h8 r2; bool g2 = (tid+512) < 640;
    #pragma unroll
    for (int e=0;e<8;e++) r2[e] = (_Float16)0.f;
    if (g2) r2 = *(const h8*)(Wb + (size_t)(tid+512)*8);
    __syncthreads();                        // h1 writes + last L1 Bs reads done
    _Float16* b0p = &Bs[0][0][0];
    *(h8*)(b0p + BSOFF(tid))     = r0;
    *(h8*)(b0p + BSOFF(tid+256)) = r1;
    if (g2) *(h8*)(b0p + BSOFF(tid+512)) = r2;
    __syncthreads();
    int cur = 0;
    int xr = rA & 7;
    for (int kt=0; kt<6; ++kt){
      h8 a = *(const h8*)(&h1l[rA][0] + (((kt*4 + lg) ^ xr)<<3));
      if (kt < 5){
        const _Float16* src = Wb + (size_t)(kt+1)*160*32;
        r0 = *(const h8*)(src + (size_t)tid*8);
        r1 = *(const h8*)(src + (size_t)(tid+256)*8);
        if (g2) r2 = *(const h8*)(src + (size_t)(tid+512)*8);
      }
      const _Float16* bb = &Bs[cur][0][0];
      #pragma unroll
      for (int c=0;c<5;c++){
        h8 bf = *(const h8*)(bb + (ch*80 + c*16 + lr16)*36 + lg*8);
        acc[c] = __builtin_amdgcn_mfma_f32_16x16x32_f16(a, bf, acc[c], 0, 0, 0);
      }
      if (kt < 5){
        _Float16* bn = &Bs[cur^1][0][0];
        *(h8*)(bn + BSOFF(tid))     = r0;
        *(h8*)(bn + BSOFF(tid+256)) = r1;
        if (g2) *(h8*)(bn + BSOFF(tid+512)) = r2;
        __syncthreads();
        cur ^= 1;
      }
    }
    const float* bias = B2 + s*160;
    #pragma unroll
    for (int c=0;c<5;c++){
      int col = ch*80 + c*16 + lr16;
      float bv = bias[col];
      #pragma unroll
      for (int rr=0;rr<4;rr++){
        int r = rW + rr;
        float v = acc[c][rr] + bv;
        v = v > 0.f ? v : 0.1f*expm1f(v*10.f);
        int pc = (((col>>3) ^ (r&7))<<3) | (col&7);
        h2l[r*256 + pc] = (_Float16)v;
      }
    }
  }
  __syncthreads();
  // ---------------- L3: 160 -> 1 ----------------
  {
    int row = tid>>3, sub = tid&7;
    if (row < mrem){
      const float* w3 = W3 + s*160;
      int xr = row & 7;
      float v = 0.f;
      #pragma unroll
      for (int e=0;e<20;e++){
        int k = sub*20 + e;
        int pc = (((k>>3) ^ xr)<<3) | (k&7);
        v += (float)h2l[row*256 + pc] * w3[k];
      }
      #pragma unroll
      for (int o=1;o<8;o<<=1) v += __shfl_xor(v, o);
      if (sub == 0) outv[idxarr[row0+row]] = v + b3[s];
    }
  }
}

// ---- fused charge iteration (512 thr): qupdate + esp(8-way) + qraev(recurrence, 2x4 split) ----
__global__ void iter_kernel(const float* __restrict__ chi, const float* __restrict__ invj,
                            const float* __restrict__ pmf, const float* __restrict__ netq,
                            const float* __restrict__ dbuf, const float* __restrict__ sig,
                            float* __restrict__ q, _Float16* __restrict__ feat){
  int m = blockIdx.x, tid = threadIdx.x;
  int i = tid & 63, w = tid >> 6;   // w in 0..7
  __shared__ float qs[64], pms[64], sg2[64];
  __shared__ float esp8[8][64];
  __shared__ float qr[8][64][8];
  if (tid < 64){
    int g = m*64 + i;
    float pm = pmf[g], ij = invj[g];
    float c = pm > 0.f ? chi[g] : 0.f;
    float num = wsum(c*ij);
    float den = wsum(ij*pm);
    float corr = (netq[m] + num) / den;
    float qa = -ij*(c - corr)*pm;
    q[g] = qa;
    feat[(size_t)g*FK + 416] = (_Float16)qa;
    qs[i] = qa; pms[i] = pm;
    float s0 = sig[g]; sg2[i] = s0*s0;
  }
  __syncthreads();
  const float* dr = dbuf + (size_t)m*4096;
  {
    float si2 = sg2[i];
    float acc = 0.f;
    #pragma unroll
    for (int jj=0;jj<8;jj++){
      int j = w*8 + jj;
      if (j==i) continue;
      float d = dr[j*64 + i];
      float ss = fmaxf(si2 + sg2[j], 1e-8f);
      acc += qs[j]*pms[j]*erff(d/sqrtf(2.f*ss))/d;
    }
    esp8[w][i] = acc;
  }
  {
    const float STEP = 0.264516129f;     // 8.2/31
    const float C2 = 0.7558781f;         // exp(-4*STEP^2)
    const float C1 = 0.5713518f;         // exp(-8*STEP^2)
    int jh = w>>2, bg = w&3;
    float rbase = 0.8f + (bg*8)*STEP;
    float pmi = pms[i];
    float acc[8] = {0.f,0.f,0.f,0.f,0.f,0.f,0.f,0.f};
    for (int jj=0;jj<32;jj++){
      int j = jh*32 + jj;
      if (j==i) continue;
      float d = dr[j*64+i];
      if (d < 10.f){
        float wq = 0.25f*(0.5f*__cosf(0.31415927f*d)+0.5f)*qs[j]*pms[j]*pmi;
        if (wq != 0.f){
          float t0 = d - rbase;
          float fv = __expf(-4.f*t0*t0);
          float gv = __expf(2.116129f*t0)*C2;
          #pragma unroll
          for (int r=0;r<8;r++){ acc[r] += wq*fv; fv *= gv; gv *= C1; }
        }
      }
    }
    #pragma unroll
    for (int r=0;r<8;r++) qr[w][i][r] = acc[r];
  }
  __syncthreads();
  if (tid < 64){
    int g = m*64+i;
    float e = 0.f;
    #pragma unroll
    for (int k=0;k<8;k++) e += esp8[k][i];
    feat[(size_t)g*FK + 417] = (_Float16)(e * pms[i]);
  }
  if (tid < 256){
    int ii = tid & 63, bg = tid >> 6;
    h8 o;
    #pragma unroll
    for (int r=0;r<8;r++) o[r] = (_Float16)(qr[bg][ii][r] + qr[bg+4][ii][r]);
    *reinterpret_cast<h8*>(feat + (size_t)(m*64+ii)*FK + 384 + bg*8) = o;
  }
}

// ---------------- screened Coulomb + energy + outputs ----------------
__global__ void final_kernel(const float* __restrict__ dbuf, const float* __restrict__ q,
                             const float* __restrict__ pmf, const float* __restrict__ ae,
                             const int* __restrict__ species, float* __restrict__ out){
  int m = blockIdx.x, a = threadIdx.x, g = m*64+a;
  __shared__ float qs[64], pms[64];
  qs[a]=q[g]; pms[a]=pmf[g];
  __syncthreads();
  float acc=0.f;
  const float* dr = dbuf + (size_t)m*4096;
  for (int b=0;b<64;b++){
    if (b==a) continue;
    float d = dr[b*64+a];
    float sgm = 1.f/(1.f+__expf(-(d-2.2f)*8.5f));
    acc += qs[b]*pms[b]*sgm/d;
  }
  float e = 0.5f*qs[a]*pms[a]*acc;
  float aea = pms[a]>0.f ? ae[g] : 0.f;
  float tot = wsum(e + aea);
  if (a == 0) out[NFLAT + m] = tot;
  out[g] = (float)species[g];
  out[NFLAT + NMOL + g] = qs[a];
}

extern "C" void kernel_launch(void* const* d_in, const int* in_sizes, int n_in,
                              void* d_out, int out_size, void* d_ws, size_t ws_size,
                              hipStream_t stream){
  const int*   species = (const int*)d_in[0];
  const float* coord   = (const float*)d_in[1];
  const float* netq    = (const float*)d_in[2];
  const float* aev     = (const float*)d_in[3];
  const float* cW[4] = {(const float*)d_in[4],(const float*)d_in[6],(const float*)d_in[8],(const float*)d_in[10]};
  const float* cB[4] = {(const float*)d_in[5],(const float*)d_in[7],(const float*)d_in[9],(const float*)d_in[11]};
  const float* aW[4] = {(const float*)d_in[12],(const float*)d_in[14],(const float*)d_in[16],(const float*)d_in[18]};
  const float* aB[4] = {(const float*)d_in[13],(const float*)d_in[15],(const float*)d_in[17],(const float*)d_in[19]};

  // workspace layout (float units; fp16 regions counted as elems/2, all 16B-aligned)
  float* f = (float*)d_ws;
  size_t o = 0;
  float* dbuf  = f + o; o += (size_t)NMOL*4096;
  float* sig   = f + o; o += NFLAT;
  float* invj  = f + o; o += NFLAT;
  float* pmf   = f + o; o += NFLAT;
  float* q     = f + o; o += NFLAT;
  float* chi   = f + o; o += NFLAT;
  _Float16* feat = (_Float16*)(f + o); o += (size_t)NFLAT*FK/2;
  // Wt[i]: [4][KT][N][32] fp16
  const int KT_[3] = {14, 8, 6};
  const int N_[3]  = {D0, D1, D2};
  _Float16* wt[6];
  for (int i=0;i<6;i++){
    wt[i] = (_Float16*)(f + o);
    o += (size_t)4*KT_[i%3]*N_[i%3]*32/2;
  }
  int* meta    = (int*)(f + o); o += 64;
  int* idxarr  = (int*)(f + o); o += MPAD;
  int* blkhist = (int*)(f + o); o += NMOL*4;
  int* blkoff  = (int*)(f + o); o += NMOL*4;

  // ---- one-time prep (per launch) ----
  cvt_aev_kernel<<<dim3(NFLAT/4), 256, 0, stream>>>(aev, feat);
  for (int i=0;i<6;i++){
    const float* Wsrc = (i<3) ? cW[i] : aW[i-3];
    int li = i%3;
    int K = (li==0) ? 418 : (li==1 ? D0 : D1);
    int N = N_[li], KT = KT_[li];
    wtrans_kernel<<<dim3((N*KT+255)/256, 4), 256, 0, stream>>>(Wsrc, wt[i], K, N, KT);
  }
  prep_kernel<<<dim3(NMOL), 256, 0, stream>>>(species, coord, dbuf, sig, invj, pmf, blkhist);
  plan_kernel<<<dim3(1), 64, 0, stream>>>(blkhist, meta, blkoff);
  scatter_kernel<<<dim3(NMOL), 64, 0, stream>>>(species, blkoff, idxarr);

  for (int pass=0; pass<3; ++pass){
    int wb = (pass<2) ? 0 : 3;
    const float* const* Bp = (pass<2) ? cB : aB;
    const float* W3 = (pass<2) ? cW[3] : aW[3];
    const float* b3 = (pass<2) ? cB[3] : aB[3];
    mlp_fused<<<dim3(1028), 256, 0, stream>>>(feat, idxarr, meta,
                                              wt[wb+0], wt[wb+1], wt[wb+2],
                                              Bp[0], Bp[1], Bp[2], W3, b3, chi);
    if (pass < 2)
      iter_kernel<<<dim3(NMOL), 512, 0, stream>>>(chi, invj, pmf, netq, dbuf, sig, q, feat);
  }
  final_kernel<<<dim3(NMOL), 64, 0, stream>>>(dbuf, q, pmf, chi, species, (float*)d_out);
}

// Round 12
// 485.839 us; speedup vs baseline: 1.2197x; 1.2197x over previous
//
#include <hip/hip_runtime.h>
#include <math.h>

#define NMOL 512
#define NATOM 64
#define NFLAT (NMOL*NATOM)
#define AEVL 384
#define FK 448           // fp16 feature row: 384 aev | 32 qraev | q | esp | 30 pad(0)
#define D0 256
#define D1 192
#define D2 160
#define MPAD 33024

typedef _Float16 h8 __attribute__((ext_vector_type(8)));
typedef float    f4 __attribute__((ext_vector_type(4)));

__constant__ float c_sigma[8] = {0.5515909f,1.8886297f,1.3225029f,1.2316629f,
                                 2.1884933f,1.7750372f,1.3677907f,1.3820058f};

__device__ __forceinline__ float wsum(float v){
  #pragma unroll
  for (int o=1;o<64;o<<=1) v += __shfl_xor(v,o);
  return v;
}

// ---------------- AEV -> fp16 feature rows (tail 384..447 zeroed) ----------------
__global__ void cvt_aev_kernel(const float* __restrict__ aev, _Float16* __restrict__ feat){
  int atom = blockIdx.x*4 + (threadIdx.x>>6);
  int c = threadIdx.x & 63;
  if (c >= 56) return;
  int k8 = c*8;
  h8 o;
  if (k8 < AEVL){
    const f4* s = reinterpret_cast<const f4*>(aev + (size_t)atom*AEVL + k8);
    f4 a = s[0], b = s[1];
    o[0]=(_Float16)a[0]; o[1]=(_Float16)a[1]; o[2]=(_Float16)a[2]; o[3]=(_Float16)a[3];
    o[4]=(_Float16)b[0]; o[5]=(_Float16)b[1]; o[6]=(_Float16)b[2]; o[7]=(_Float16)b[3];
  } else {
    #pragma unroll
    for (int i=0;i<8;i++) o[i] = (_Float16)0.f;
  }
  *reinterpret_cast<h8*>(feat + (size_t)atom*FK + k8) = o;
}

// ---- W [4][K][N] f32 -> Wt [4][KT][N][32] fp16 (k-step tiles contiguous, zero-padded) ----
__global__ void wtrans_kernel(const float* __restrict__ W, _Float16* __restrict__ Wt,
                              int K, int N, int KT){
  int pair = blockIdx.x*256 + threadIdx.x;
  if (pair >= N*KT) return;
  int col = pair % N;
  int kb  = pair / N;
  int s = blockIdx.y;
  h8 o[4];
  #pragma unroll
  for (int g=0; g<4; ++g){
    #pragma unroll
    for (int e=0; e<8; ++e){
      int gk = kb*32 + g*8 + e;
      float v = (gk < K) ? W[((size_t)s*K + gk)*N + col] : 0.f;
      o[g][e] = (_Float16)v;
    }
  }
  _Float16* dst = Wt + (((size_t)s*KT + kb)*N + col)*32;
  #pragma unroll
  for (int g=0; g<4; ++g) *reinterpret_cast<h8*>(dst + g*8) = o[g];
}

// ---------------- distances + per-atom species data + per-molecule histogram ----------------
__global__ void prep_kernel(const int* __restrict__ species,
                            const float* __restrict__ coord,
                            float* __restrict__ dbuf, float* __restrict__ sig,
                            float* __restrict__ invj, float* __restrict__ pmf,
                            int* __restrict__ blkhist){
  int m = blockIdx.x, t = threadIdx.x;
  __shared__ float c[192];
  if (t < 192) c[t] = coord[m*192 + t];
  __syncthreads();
  #pragma unroll
  for (int k=0;k<16;k++){
    int p = t + 256*k;
    int i = p >> 6, j = p & 63;
    float dx=c[i*3]-c[j*3], dy=c[i*3+1]-c[j*3+1], dz=c[i*3+2]-c[j*3+2];
    dbuf[m*4096 + p] = sqrtf(dx*dx+dy*dy+dz*dz + 1e-16f) / 0.529177249f;
  }
  if (t < 64){
    int g = m*64+t;
    int s = species[g];
    float sg = c_sigma[s < 0 ? 7 : s];
    sig[g]  = sg;
    invj[g] = 1.7724539f * sg;   // sqrt(pi) fp32
    pmf[g]  = (s>=0) ? 1.f : 0.f;
    #pragma unroll
    for (int sp=0;sp<4;sp++){
      unsigned long long mask = __ballot(s==sp);
      if (t==0) blkhist[m*4+sp] = __popcll(mask);
    }
  }
}

// ---------------- plan: 64-aligned bases (round-10 semantics) ----------------
// meta: [0..3] counts, [4..8] base(64-aligned, [8]=total rows), [9..13] tile_base ([13]=total tiles)
__global__ void plan_kernel(const int* __restrict__ blkhist, int* __restrict__ meta,
                            int* __restrict__ blkoff){
  __shared__ int tot[4], base[4];
  int t = threadIdx.x;
  if (t < 4){
    int sum = 0;
    for (int m=0;m<NMOL;m++) sum += blkhist[m*4+t];
    tot[t] = sum;
  }
  __syncthreads();
  if (t == 0){
    int b=0, tb=0;
    meta[4]=0; meta[9]=0;
    for (int s=0;s<4;s++){
      meta[s] = tot[s];
      base[s] = b;
      int tiles = (tot[s]+63)>>6;
      b  += tiles<<6;  tb += tiles;
      meta[5+s]  = b;  meta[10+s] = tb;
    }
  }
  __syncthreads();
  if (t < 4){
    int run = base[t];
    for (int m=0;m<NMOL;m++){ blkoff[m*4+t] = run; run += blkhist[m*4+t]; }
  }
}

// ---------------- deterministic atomic-free scatter ----------------
__global__ void scatter_kernel(const int* __restrict__ species,
                               const int* __restrict__ blkoff,
                               int* __restrict__ idxarr){
  int m = blockIdx.x, a = threadIdx.x, g = m*64+a;
  int s = species[g];
  unsigned long long below = (1ull<<a) - 1ull;
  #pragma unroll
  for (int sp=0;sp<4;sp++){
    unsigned long long mask = __ballot(s==sp);
    if (s==sp){
      int rank = __popcll(mask & below);
      idxarr[blkoff[m*4+sp] + rank] = g;
    }
  }
}

// ======== persistent-W fp16 MFMA GEMM: block = (col-slice, species, r); W-slice LDS-resident ========
// Stage W[s][:, c0:c0+COLS] once (one barrier), then loop row tiles of species s with ZERO barriers.
// Per k-step/wave: 1 preloaded A-frag + NCB ds_read_b128 + NCB MFMA.
template<int GATHER, int NCB, int KT, int R>   // COLS=NCB*16; grid = (N/COLS)*4*R
__launch_bounds__(256)
__global__ void gemm_pw(const _Float16* __restrict__ Ah,    // [rows][KT*32]  (GATHER=0)
                        const _Float16* __restrict__ feat,  // [NFLAT][FK]    (GATHER=1)
                        const int* __restrict__ idxarr,
                        const int* __restrict__ meta,
                        const _Float16* __restrict__ Wt,    // [4][KT][N][32]
                        const float* __restrict__ Ball,     // [4][N]
                        _Float16* __restrict__ C,           // [rows][N]
                        int N, int act){
  constexpr int COLS = NCB*16;
  constexpr int NCHUNK = KT*COLS*4;      // h8 chunks in the W slice
  __shared__ _Float16 Ws[KT*COLS*36/32*32 + 32];  // [KT][COLS][36] halves

  int bx = blockIdx.x;
  int slices = N / COLS;
  int cs = bx % slices;
  int rest = bx / slices;
  int s = rest & 3;
  int r = rest >> 2;
  int c0 = cs * COLS;

  int tid = threadIdx.x;
  // ---- stage W slice (once) ----
  for (int j = tid; j < NCHUNK; j += 256){
    int kt  = j / (COLS*4);
    int rem = j - kt*(COLS*4);
    int col = rem >> 2, part = rem & 3;
    h8 v = *reinterpret_cast<const h8*>(Wt + (((size_t)s*KT + kt)*N + c0 + col)*32 + part*8);
    *reinterpret_cast<h8*>(&Ws[(kt*COLS + col)*36 + part*8]) = v;
  }
  __syncthreads();

  int cnt = meta[s];
  if (cnt == 0) return;
  int nt = (cnt + 63) >> 6;
  int base = meta[4+s];
  const float* bias = Ball + s*N;

  int w = tid>>6, l = tid&63, lr16 = l&15, lg = l>>4;

  int cur_idx = 0;
  if (GATHER && r < nt){
    int row0 = base + (r<<6);
    int mrem = cnt - (r<<6); if (mrem > 64) mrem = 64;
    int arow = row0 + w*16 + lr16;
    int amax = row0 + mrem - 1;
    if (arow > amax) arow = amax;
    cur_idx = idxarr[arow];
  }

  for (int t = r; t < nt; t += R){
    int row0 = base + (t<<6);
    int mrem = cnt - (t<<6); if (mrem > 64) mrem = 64;
    const _Float16* ap;
    if (GATHER){
      ap = feat + (size_t)cur_idx*FK + lg*8;
    } else {
      int arow = row0 + w*16 + lr16;
      int amax = row0 + mrem - 1;
      if (arow > amax) arow = amax;
      ap = Ah + (size_t)arow*(KT*32) + lg*8;
    }
    // prefetch next tile's gather index during this tile's compute
    if (GATHER && t + R < nt){
      int nrow0 = base + ((t+R)<<6);
      int nrem  = cnt - ((t+R)<<6); if (nrem > 64) nrem = 64;
      int narow = nrow0 + w*16 + lr16;
      int namax = nrow0 + nrem - 1;
      if (narow > namax) narow = namax;
      cur_idx = idxarr[narow];
    }

    f4 acc[NCB];
    #pragma unroll
    for (int c=0;c<NCB;c++){ acc[c][0]=0.f; acc[c][1]=0.f; acc[c][2]=0.f; acc[c][3]=0.f; }

    h8 aF0 = *reinterpret_cast<const h8*>(ap);
    h8 aF1;
    if (KT > 1) aF1 = *reinterpret_cast<const h8*>(ap + 32);
    #pragma unroll
    for (int kt=0; kt<KT; ++kt){
      h8 a = (kt & 1) ? aF1 : aF0;
      if (kt + 2 < KT){
        if (kt & 1) aF1 = *reinterpret_cast<const h8*>(ap + (kt+2)*32);
        else        aF0 = *reinterpret_cast<const h8*>(ap + (kt+2)*32);
      }
      #pragma unroll
      for (int c=0;c<NCB;c++){
        h8 bf = *reinterpret_cast<const h8*>(&Ws[(kt*COLS + c*16 + lr16)*36 + lg*8]);
        acc[c] = __builtin_amdgcn_mfma_f32_16x16x32_f16(a, bf, acc[c], 0, 0, 0);
      }
    }
    // epilogue: C/D layout col=lane&15, row=(lane>>4)*4+reg (HW-verified)
    #pragma unroll
    for (int c=0;c<NCB;c++){
      int col = c0 + c*16 + lr16;
      float bsv = bias[col];
      #pragma unroll
      for (int rr=0;rr<4;rr++){
        int lrow = w*16 + lg*4 + rr;
        if (lrow >= mrem) continue;
        float vv = acc[c][rr] + bsv;
        if (act) vv = vv > 0.f ? vv : 0.1f*expm1f(vv*10.f);
        C[(size_t)(row0+lrow)*N + col] = (_Float16)vv;
      }
    }
  }
}

// ---------------- output layer: 160 -> 1 dot per row (fp16 h), scatter to atom ----------------
__global__ void layer3_kernel(const _Float16* __restrict__ h2,
                              const int* __restrict__ idxarr,
                              const int* __restrict__ meta,
                              const float* __restrict__ W3,  // [4][160]
                              const float* __restrict__ b3,  // [4]
                              float* __restrict__ outv){
  int row = blockIdx.x*4 + (threadIdx.x>>6);
  int lane = threadIdx.x & 63;
  if (row >= meta[8]) return;
  int s = 0;
  while (s < 3 && row >= meta[5+s]) s++;
  int lrow = row - meta[4+s];
  if (lrow >= meta[s]) return;
  const _Float16* h = h2 + (size_t)row*D2;
  const float* w = W3 + s*D2;
  float v = (float)h[lane]*w[lane] + (float)h[lane+64]*w[lane+64];
  if (lane < 32) v += (float)h[lane+128]*w[lane+128];
  v = wsum(v);
  if (lane == 0) outv[idxarr[row]] = v + b3[s];
}

// ---- fused charge iteration (512 thr): qupdate + esp(8-way) + qraev(recurrence, 2x4 split) ----
__global__ void iter_kernel(const float* __restrict__ chi, const float* __restrict__ invj,
                            const float* __restrict__ pmf, const float* __restrict__ netq,
                            const float* __restrict__ dbuf, const float* __restrict__ sig,
                            float* __restrict__ q, _Float16* __restrict__ feat){
  int m = blockIdx.x, tid = threadIdx.x;
  int i = tid & 63, w = tid >> 6;   // w in 0..7
  __shared__ float qs[64], pms[64], sg2[64];
  __shared__ float esp8[8][64];
  __shared__ float qr[8][64][8];
  if (tid < 64){
    int g = m*64 + i;
    float pm = pmf[g], ij = invj[g];
    float c = pm > 0.f ? chi[g] : 0.f;
    float num = wsum(c*ij);
    float den = wsum(ij*pm);
    float corr = (netq[m] + num) / den;
    float qa = -ij*(c - corr)*pm;
    q[g] = qa;
    feat[(size_t)g*FK + 416] = (_Float16)qa;
    qs[i] = qa; pms[i] = pm;
    float s0 = sig[g]; sg2[i] = s0*s0;
  }
  __syncthreads();
  const float* dr = dbuf + (size_t)m*4096;
  {
    float si2 = sg2[i];
    float acc = 0.f;
    #pragma unroll
    for (int jj=0;jj<8;jj++){
      int j = w*8 + jj;
      if (j==i) continue;
      float d = dr[j*64 + i];
      float ss = fmaxf(si2 + sg2[j], 1e-8f);
      acc += qs[j]*pms[j]*erff(d/sqrtf(2.f*ss))/d;
    }
    esp8[w][i] = acc;
  }
  {
    const float STEP = 0.264516129f;     // 8.2/31
    const float C2 = 0.7558781f;         // exp(-4*STEP^2)
    const float C1 = 0.5713518f;         // exp(-8*STEP^2)
    int jh = w>>2, bg = w&3;
    float rbase = 0.8f + (bg*8)*STEP;
    float pmi = pms[i];
    float acc[8] = {0.f,0.f,0.f,0.f,0.f,0.f,0.f,0.f};
    for (int jj=0;jj<32;jj++){
      int j = jh*32 + jj;
      if (j==i) continue;
      float d = dr[j*64+i];
      if (d < 10.f){
        float wq = 0.25f*(0.5f*__cosf(0.31415927f*d)+0.5f)*qs[j]*pms[j]*pmi;
        if (wq != 0.f){
          float t0 = d - rbase;
          float fv = __expf(-4.f*t0*t0);
          float gv = __expf(2.116129f*t0)*C2;
          #pragma unroll
          for (int r=0;r<8;r++){ acc[r] += wq*fv; fv *= gv; gv *= C1; }
        }
      }
    }
    #pragma unroll
    for (int r=0;r<8;r++) qr[w][i][r] = acc[r];
  }
  __syncthreads();
  if (tid < 64){
    int g = m*64+i;
    float e = 0.f;
    #pragma unroll
    for (int k=0;k<8;k++) e += esp8[k][i];
    feat[(size_t)g*FK + 417] = (_Float16)(e * pms[i]);
  }
  if (tid < 256){
    int ii = tid & 63, bg = tid >> 6;
    h8 o;
    #pragma unroll
    for (int r=0;r<8;r++) o[r] = (_Float16)(qr[bg][ii][r] + qr[bg+4][ii][r]);
    *reinterpret_cast<h8*>(feat + (size_t)(m*64+ii)*FK + 384 + bg*8) = o;
  }
}

// ---------------- screened Coulomb + energy + outputs ----------------
__global__ void final_kernel(const float* __restrict__ dbuf, const float* __restrict__ q,
                             const float* __restrict__ pmf, const float* __restrict__ ae,
                             const int* __restrict__ species, float* __restrict__ out){
  int m = blockIdx.x, a = threadIdx.x, g = m*64+a;
  __shared__ float qs[64], pms[64];
  qs[a]=q[g]; pms[a]=pmf[g];
  __syncthreads();
  float acc=0.f;
  const float* dr = dbuf + (size_t)m*4096;
  for (int b=0;b<64;b++){
    if (b==a) continue;
    float d = dr[b*64+a];
    float sgm = 1.f/(1.f+__expf(-(d-2.2f)*8.5f));
    acc += qs[b]*pms[b]*sgm/d;
  }
  float e = 0.5f*qs[a]*pms[a]*acc;
  float aea = pms[a]>0.f ? ae[g] : 0.f;
  float tot = wsum(e + aea);
  if (a == 0) out[NFLAT + m] = tot;
  out[g] = (float)species[g];
  out[NFLAT + NMOL + g] = qs[a];
}

extern "C" void kernel_launch(void* const* d_in, const int* in_sizes, int n_in,
                              void* d_out, int out_size, void* d_ws, size_t ws_size,
                              hipStream_t stream){
  const int*   species = (const int*)d_in[0];
  const float* coord   = (const float*)d_in[1];
  const float* netq    = (const float*)d_in[2];
  const float* aev     = (const float*)d_in[3];
  const float* cW[4] = {(const float*)d_in[4],(const float*)d_in[6],(const float*)d_in[8],(const float*)d_in[10]};
  const float* cB[4] = {(const float*)d_in[5],(const float*)d_in[7],(const float*)d_in[9],(const float*)d_in[11]};
  const float* aW[4] = {(const float*)d_in[12],(const float*)d_in[14],(const float*)d_in[16],(const float*)d_in[18]};
  const float* aB[4] = {(const float*)d_in[13],(const float*)d_in[15],(const float*)d_in[17],(const float*)d_in[19]};

  // workspace layout (float units; fp16 regions counted as elems/2, all 16B-aligned)
  float* f = (float*)d_ws;
  size_t o = 0;
  float* dbuf  = f + o; o += (size_t)NMOL*4096;
  float* sig   = f + o; o += NFLAT;
  float* invj  = f + o; o += NFLAT;
  float* pmf   = f + o; o += NFLAT;
  float* q     = f + o; o += NFLAT;
  float* chi   = f + o; o += NFLAT;
  _Float16* feat = (_Float16*)(f + o); o += (size_t)NFLAT*FK/2;
  _Float16* h0h  = (_Float16*)(f + o); o += (size_t)MPAD*D0/2;
  _Float16* h1h  = (_Float16*)(f + o); o += (size_t)MPAD*D1/2;
  _Float16* h2h  = h0h;   // layer2 writes over h0 (already consumed)
  // Wt[i]: [4][KT][N][32] fp16
  const int KT_[3] = {14, 8, 6};
  const int N_[3]  = {D0, D1, D2};
  _Float16* wt[6];
  for (int i=0;i<6;i++){
    wt[i] = (_Float16*)(f + o);
    o += (size_t)4*KT_[i%3]*N_[i%3]*32/2;
  }
  int* meta    = (int*)(f + o); o += 64;
  int* idxarr  = (int*)(f + o); o += MPAD;
  int* blkhist = (int*)(f + o); o += NMOL*4;
  int* blkoff  = (int*)(f + o); o += NMOL*4;

  // ---- one-time prep (per launch) ----
  cvt_aev_kernel<<<dim3(NFLAT/4), 256, 0, stream>>>(aev, feat);
  for (int i=0;i<6;i++){
    const float* Wsrc = (i<3) ? cW[i] : aW[i-3];
    int li = i%3;
    int K = (li==0) ? 418 : (li==1 ? D0 : D1);
    int N = N_[li], KT = KT_[li];
    wtrans_kernel<<<dim3((N*KT+255)/256, 4), 256, 0, stream>>>(Wsrc, wt[i], K, N, KT);
  }
  prep_kernel<<<dim3(NMOL), 256, 0, stream>>>(species, coord, dbuf, sig, invj, pmf, blkhist);
  plan_kernel<<<dim3(1), 64, 0, stream>>>(blkhist, meta, blkoff);
  scatter_kernel<<<dim3(NMOL), 64, 0, stream>>>(species, blkoff, idxarr);

  for (int pass=0; pass<3; ++pass){
    int wb = (pass<2) ? 0 : 3;
    const float* const* Bp = (pass<2) ? cB : aB;
    // L0: 4 col-slices x 4 species x R=33 -> 528 blocks
    gemm_pw<1,4,14,33><<<dim3(528), 256, 0, stream>>>(nullptr, feat, idxarr, meta,
                                                      wt[wb+0], Bp[0], h0h, D0, 1);
    // L1: 2 slices (96 cols) x 4 x R=64 -> 512 blocks
    gemm_pw<0,6,8,64><<<dim3(512), 256, 0, stream>>>(h0h, nullptr, idxarr, meta,
                                                     wt[wb+1], Bp[1], h1h, D1, 1);
    // L2: 2 slices (80 cols) x 4 x R=64 -> 512 blocks
    gemm_pw<0,5,6,64><<<dim3(512), 256, 0, stream>>>(h1h, nullptr, idxarr, meta,
                                                     wt[wb+2], Bp[2], h2h, D2, 1);
    layer3_kernel<<<dim3(MPAD/4), 256, 0, stream>>>(h2h, idxarr, meta, (pass<2)?cW[3]:aW[3],
                                                    (pass<2)?cB[3]:aB[3], chi);
    if (pass < 2)
      iter_kernel<<<dim3(NMOL), 512, 0, stream>>>(chi, invj, pmf, netq, dbuf, sig, q, feat);
  }
  final_kernel<<<dim3(NMOL), 64, 0, stream>>>(dbuf, q, pmf, chi, species, (float*)d_out);
}

// Round 13
// 308.348 us; speedup vs baseline: 1.9219x; 1.5756x over previous
//
#include <hip/hip_runtime.h>
#include <math.h>

#define NMOL 512
#define NATOM 64
#define NFLAT (NMOL*NATOM)
#define AEVL 384
#define FK 448           // fp16 feature row: 384 aev | 32 qraev | q | esp | 30 pad(0)
#define D0 256
#define D1 192
#define D2 160
#define MPAD 33024

typedef _Float16 h8 __attribute__((ext_vector_type(8)));
typedef float    f4 __attribute__((ext_vector_type(4)));

__constant__ float c_sigma[8] = {0.5515909f,1.8886297f,1.3225029f,1.2316629f,
                                 2.1884933f,1.7750372f,1.3677907f,1.3820058f};

__device__ __forceinline__ float wsum(float v){
  #pragma unroll
  for (int o=1;o<64;o<<=1) v += __shfl_xor(v,o);
  return v;
}

// direct global->LDS copy, 16B per lane; lds base must be wave-uniform
__device__ __forceinline__ void gll16(const _Float16* g, _Float16* l){
  __builtin_amdgcn_global_load_lds(
    (const __attribute__((address_space(1))) void*)g,
    (__attribute__((address_space(3))) void*)l, 16, 0, 0);
}

// ---------------- AEV -> fp16 feature rows (tail 384..447 zeroed) ----------------
__global__ void cvt_aev_kernel(const float* __restrict__ aev, _Float16* __restrict__ feat){
  int atom = blockIdx.x*4 + (threadIdx.x>>6);
  int c = threadIdx.x & 63;
  if (c >= 56) return;
  int k8 = c*8;
  h8 o;
  if (k8 < AEVL){
    const f4* s = reinterpret_cast<const f4*>(aev + (size_t)atom*AEVL + k8);
    f4 a = s[0], b = s[1];
    o[0]=(_Float16)a[0]; o[1]=(_Float16)a[1]; o[2]=(_Float16)a[2]; o[3]=(_Float16)a[3];
    o[4]=(_Float16)b[0]; o[5]=(_Float16)b[1]; o[6]=(_Float16)b[2]; o[7]=(_Float16)b[3];
  } else {
    #pragma unroll
    for (int i=0;i<8;i++) o[i] = (_Float16)0.f;
  }
  *reinterpret_cast<h8*>(feat + (size_t)atom*FK + k8) = o;
}

// ---- W [4][K][N] f32 -> Wt [4][KT][4part][N][8] fp16 (linear-stageable, zero-padded) ----
// unit u = (kt*4+part)*N + col holds k-range kt*32+part*8 .. +8 for column col.
__global__ void wtrans_kernel(const float* __restrict__ Wc, const float* __restrict__ Wa,
                              _Float16* __restrict__ WtC, _Float16* __restrict__ WtA,
                              int K, int N, int KT){
  int u = blockIdx.x*256 + threadIdx.x;
  if (u >= KT*4*N) return;
  int col = u % N;
  int pk  = u / N;           // kt*4+part
  int part = pk & 3, kt = pk >> 2;
  int s = blockIdx.y;
  const float* W = (blockIdx.z == 0) ? Wc : Wa;
  _Float16* Wt   = (blockIdx.z == 0) ? WtC : WtA;
  h8 o;
  #pragma unroll
  for (int e=0;e<8;e++){
    int gk = kt*32 + part*8 + e;
    float v = (gk < K) ? W[((size_t)s*K + gk)*N + col] : 0.f;
    o[e] = (_Float16)v;
  }
  *reinterpret_cast<h8*>(Wt + ((size_t)s*KT*4 + pk)*N*8 + (size_t)col*8) = o;
}

// ---------------- distances + per-atom species data + per-molecule histogram ----------------
__global__ void prep_kernel(const int* __restrict__ species,
                            const float* __restrict__ coord,
                            float* __restrict__ dbuf, float* __restrict__ sig,
                            float* __restrict__ invj, float* __restrict__ pmf,
                            int* __restrict__ blkhist){
  int m = blockIdx.x, t = threadIdx.x;
  __shared__ float c[192];
  if (t < 192) c[t] = coord[m*192 + t];
  __syncthreads();
  #pragma unroll
  for (int k=0;k<16;k++){
    int p = t + 256*k;
    int i = p >> 6, j = p & 63;
    float dx=c[i*3]-c[j*3], dy=c[i*3+1]-c[j*3+1], dz=c[i*3+2]-c[j*3+2];
    dbuf[m*4096 + p] = sqrtf(dx*dx+dy*dy+dz*dz + 1e-16f) / 0.529177249f;
  }
  if (t < 64){
    int g = m*64+t;
    int s = species[g];
    float sg = c_sigma[s < 0 ? 7 : s];
    sig[g]  = sg;
    invj[g] = 1.7724539f * sg;   // sqrt(pi) fp32
    pmf[g]  = (s>=0) ? 1.f : 0.f;
    #pragma unroll
    for (int sp=0;sp<4;sp++){
      unsigned long long mask = __ballot(s==sp);
      if (t==0) blkhist[m*4+sp] = __popcll(mask);
    }
  }
}

// ---------------- plan: 64-aligned bases ----------------
// meta: [0..3] counts, [4..8] base(64-aligned, [8]=total rows), [9..13] tile_base ([13]=total tiles)
__global__ void plan_kernel(const int* __restrict__ blkhist, int* __restrict__ meta,
                            int* __restrict__ blkoff){
  __shared__ int tot[4], base[4];
  int t = threadIdx.x;
  if (t < 4){
    int sum = 0;
    for (int m=0;m<NMOL;m++) sum += blkhist[m*4+t];
    tot[t] = sum;
  }
  __syncthreads();
  if (t == 0){
    int b=0, tb=0;
    meta[4]=0; meta[9]=0;
    for (int s=0;s<4;s++){
      meta[s] = tot[s];
      base[s] = b;
      int tiles = (tot[s]+63)>>6;
      b  += tiles<<6;  tb += tiles;
      meta[5+s]  = b;  meta[10+s] = tb;
    }
  }
  __syncthreads();
  if (t < 4){
    int run = base[t];
    for (int m=0;m<NMOL;m++){ blkoff[m*4+t] = run; run += blkhist[m*4+t]; }
  }
}

// ---------------- deterministic atomic-free scatter ----------------
__global__ void scatter_kernel(const int* __restrict__ species,
                               const int* __restrict__ blkoff,
                               int* __restrict__ idxarr){
  int m = blockIdx.x, a = threadIdx.x, g = m*64+a;
  int s = species[g];
  unsigned long long below = (1ull<<a) - 1ull;
  #pragma unroll
  for (int sp=0;sp<4;sp++){
    unsigned long long mask = __ballot(s==sp);
    if (s==sp){
      int rank = __popcll(mask & below);
      idxarr[blkoff[m*4+sp] + rank] = g;
    }
  }
}

// ======== m97-style fp16 MFMA GEMM: A+B staged via global_load_lds, dbuf, 1 barrier/k-step ========
// Block: 64 rows x COLS cols (COLS=NCB*16), 4 waves; wave w: rows [w*16,+16) x all COLS.
// LDS layouts (16B units): A[part4][64 rows], B[part4][COLS] -> frag reads 2-way (free).
template<int GATHER, int NCB, int KTW>
__launch_bounds__(256)
__global__ void gemm_gll(const _Float16* __restrict__ Ah,    // [rows][KTW*32]  (GATHER=0)
                         const _Float16* __restrict__ feat,  // [NFLAT][FK]     (GATHER=1)
                         const int* __restrict__ idxarr,
                         const int* __restrict__ meta,
                         const _Float16* __restrict__ Wt,    // [4][KTW*4][N][8]
                         const float* __restrict__ Ball,     // [4][N]
                         _Float16* __restrict__ C,           // [rows][N]
                         int N, int ktrun, int act){
  constexpr int COLS = NCB*16;
  constexpr int NB16 = COLS/16;          // 1KB-instructions per B k-tile
  int t = blockIdx.x;
  if (t >= meta[13]) return;
  int s = 0;
  while (s < 3 && t >= meta[10+s]) s++;
  int trow = t - meta[9+s];
  int row0 = meta[4+s] + (trow<<6);
  int mrem = meta[s] - (trow<<6); if (mrem > 64) mrem = 64;
  int c0 = blockIdx.y * COLS;

  __shared__ __align__(16) _Float16 Ab[2][2048];        // [part][row][8]
  __shared__ __align__(16) _Float16 Bb[2][COLS*32];     // [part][col][8]

  int tid = threadIdx.x;
  int w = tid>>6, l = tid&63, lr16 = l&15, lg = l>>4;

  // per-lane A source row (lane = row within tile)
  int arow = row0 + l;
  int amax = row0 + mrem - 1;
  if (arow > amax) arow = amax;
  const _Float16* asrc;
  if (GATHER) asrc = feat + (size_t)idxarr[arow]*FK;
  else        asrc = Ah + (size_t)arow*(KTW*32);

  const _Float16* Wbase = Wt + (size_t)s*KTW*4*N*8 + (size_t)c0*8;

  // stage k-step kt into buffer buf
  auto STAGE = [&](int buf, int kt){
    // A: instruction j=w covers part w, rows=lanes
    gll16(asrc + kt*32 + w*8, &Ab[buf][w*512]);
    // B: instructions j = w, w+4, ...
    for (int j=w; j<NB16; j+=4){
      int u = j*64 + l;
      int part = u / COLS, col = u - part*COLS;
      gll16(Wbase + ((size_t)(kt*4+part)*N + col)*8, &Bb[buf][j*512]);
    }
  };

  f4 acc[NCB];
  #pragma unroll
  for (int c=0;c<NCB;c++){ acc[c][0]=0.f; acc[c][1]=0.f; acc[c][2]=0.f; acc[c][3]=0.f; }

  STAGE(0, 0);
  __syncthreads();
  int cur = 0;
  for (int kt=0; kt<ktrun; ++kt){
    if (kt+1 < ktrun) STAGE(cur^1, kt+1);
    h8 aF = *reinterpret_cast<const h8*>(&Ab[cur][lg*512 + (w*16+lr16)*8]);
    #pragma unroll
    for (int c=0;c<NCB;c++){
      h8 bF = *reinterpret_cast<const h8*>(&Bb[cur][lg*COLS*8 + (c*16+lr16)*8]);
      acc[c] = __builtin_amdgcn_mfma_f32_16x16x32_f16(aF, bF, acc[c], 0, 0, 0);
    }
    if (kt+1 < ktrun){
      __syncthreads();
      cur ^= 1;
    }
  }

  // epilogue: C/D layout col=lane&15, row=(lane>>4)*4+reg (HW-verified)
  const float* bias = Ball + s*N;
  #pragma unroll
  for (int c=0;c<NCB;c++){
    int col = c0 + c*16 + lr16;
    float bsv = bias[col];
    #pragma unroll
    for (int rr=0;rr<4;rr++){
      int lrow = w*16 + lg*4 + rr;
      if (lrow >= mrem) continue;
      float vv = acc[c][rr] + bsv;
      if (act) vv = vv > 0.f ? vv : 0.1f*expm1f(vv*10.f);
      C[(size_t)(row0+lrow)*N + col] = (_Float16)vv;
    }
  }
}

// ---------------- output layer: 160 -> 1 dot per row (fp16 h), scatter to atom ----------------
__global__ void layer3_kernel(const _Float16* __restrict__ h2,
                              const int* __restrict__ idxarr,
                              const int* __restrict__ meta,
                              const float* __restrict__ W3,  // [4][160]
                              const float* __restrict__ b3,  // [4]
                              float* __restrict__ outv){
  int row = blockIdx.x*4 + (threadIdx.x>>6);
  int lane = threadIdx.x & 63;
  if (row >= meta[8]) return;
  int s = 0;
  while (s < 3 && row >= meta[5+s]) s++;
  int lrow = row - meta[4+s];
  if (lrow >= meta[s]) return;
  const _Float16* h = h2 + (size_t)row*D2;
  const float* w = W3 + s*D2;
  float v = (float)h[lane]*w[lane] + (float)h[lane+64]*w[lane+64];
  if (lane < 32) v += (float)h[lane+128]*w[lane+128];
  v = wsum(v);
  if (lane == 0) outv[idxarr[row]] = v + b3[s];
}

// ---- fused charge iteration (512 thr): qupdate + esp(8-way) + qraev(recurrence, 2x4 split) ----
__global__ void iter_kernel(const float* __restrict__ chi, const float* __restrict__ invj,
                            const float* __restrict__ pmf, const float* __restrict__ netq,
                            const float* __restrict__ dbuf, const float* __restrict__ sig,
                            float* __restrict__ q, _Float16* __restrict__ feat){
  int m = blockIdx.x, tid = threadIdx.x;
  int i = tid & 63, w = tid >> 6;   // w in 0..7
  __shared__ float qs[64], pms[64], sg2[64];
  __shared__ float esp8[8][64];
  __shared__ float qr[8][64][8];
  if (tid < 64){
    int g = m*64 + i;
    float pm = pmf[g], ij = invj[g];
    float c = pm > 0.f ? chi[g] : 0.f;
    float num = wsum(c*ij);
    float den = wsum(ij*pm);
    float corr = (netq[m] + num) / den;
    float qa = -ij*(c - corr)*pm;
    q[g] = qa;
    feat[(size_t)g*FK + 416] = (_Float16)qa;
    qs[i] = qa; pms[i] = pm;
    float s0 = sig[g]; sg2[i] = s0*s0;
  }
  __syncthreads();
  const float* dr = dbuf + (size_t)m*4096;
  {
    float si2 = sg2[i];
    float acc = 0.f;
    #pragma unroll
    for (int jj=0;jj<8;jj++){
      int j = w*8 + jj;
      if (j==i) continue;
      float d = dr[j*64 + i];
      float ss = fmaxf(si2 + sg2[j], 1e-8f);
      acc += qs[j]*pms[j]*erff(d/sqrtf(2.f*ss))/d;
    }
    esp8[w][i] = acc;
  }
  {
    const float STEP = 0.264516129f;     // 8.2/31
    const float C2 = 0.7558781f;         // exp(-4*STEP^2)
    const float C1 = 0.5713518f;         // exp(-8*STEP^2)
    int jh = w>>2, bg = w&3;
    float rbase = 0.8f + (bg*8)*STEP;
    float pmi = pms[i];
    float acc[8] = {0.f,0.f,0.f,0.f,0.f,0.f,0.f,0.f};
    for (int jj=0;jj<32;jj++){
      int j = jh*32 + jj;
      if (j==i) continue;
      float d = dr[j*64+i];
      if (d < 10.f){
        float wq = 0.25f*(0.5f*__cosf(0.31415927f*d)+0.5f)*qs[j]*pms[j]*pmi;
        if (wq != 0.f){
          float t0 = d - rbase;
          float fv = __expf(-4.f*t0*t0);
          float gv = __expf(2.116129f*t0)*C2;
          #pragma unroll
          for (int r=0;r<8;r++){ acc[r] += wq*fv; fv *= gv; gv *= C1; }
        }
      }
    }
    #pragma unroll
    for (int r=0;r<8;r++) qr[w][i][r] = acc[r];
  }
  __syncthreads();
  if (tid < 64){
    int g = m*64+i;
    float e = 0.f;
    #pragma unroll
    for (int k=0;k<8;k++) e += esp8[k][i];
    feat[(size_t)g*FK + 417] = (_Float16)(e * pms[i]);
  }
  if (tid < 256){
    int ii = tid & 63, bg = tid >> 6;
    h8 o;
    #pragma unroll
    for (int r=0;r<8;r++) o[r] = (_Float16)(qr[bg][ii][r] + qr[bg+4][ii][r]);
    *reinterpret_cast<h8*>(feat + (size_t)(m*64+ii)*FK + 384 + bg*8) = o;
  }
}

// ---------------- screened Coulomb + energy + outputs ----------------
__global__ void final_kernel(const float* __restrict__ dbuf, const float* __restrict__ q,
                             const float* __restrict__ pmf, const float* __restrict__ ae,
                             const int* __restrict__ species, float* __restrict__ out){
  int m = blockIdx.x, a = threadIdx.x, g = m*64+a;
  __shared__ float qs[64], pms[64];
  qs[a]=q[g]; pms[a]=pmf[g];
  __syncthreads();
  float acc=0.f;
  const float* dr = dbuf + (size_t)m*4096;
  for (int b=0;b<64;b++){
    if (b==a) continue;
    float d = dr[b*64+a];
    float sgm = 1.f/(1.f+__expf(-(d-2.2f)*8.5f));
    acc += qs[b]*pms[b]*sgm/d;
  }
  float e = 0.5f*qs[a]*pms[a]*acc;
  float aea = pms[a]>0.f ? ae[g] : 0.f;
  float tot = wsum(e + aea);
  if (a == 0) out[NFLAT + m] = tot;
  out[g] = (float)species[g];
  out[NFLAT + NMOL + g] = qs[a];
}

extern "C" void kernel_launch(void* const* d_in, const int* in_sizes, int n_in,
                              void* d_out, int out_size, void* d_ws, size_t ws_size,
                              hipStream_t stream){
  const int*   species = (const int*)d_in[0];
  const float* coord   = (const float*)d_in[1];
  const float* netq    = (const float*)d_in[2];
  const float* aev     = (const float*)d_in[3];
  const float* cW[4] = {(const float*)d_in[4],(const float*)d_in[6],(const float*)d_in[8],(const float*)d_in[10]};
  const float* cB[4] = {(const float*)d_in[5],(const float*)d_in[7],(const float*)d_in[9],(const float*)d_in[11]};
  const float* aW[4] = {(const float*)d_in[12],(const float*)d_in[14],(const float*)d_in[16],(const float*)d_in[18]};
  const float* aB[4] = {(const float*)d_in[13],(const float*)d_in[15],(const float*)d_in[17],(const float*)d_in[19]};

  // workspace layout (float units; fp16 regions counted as elems/2, all 16B-aligned)
  float* f = (float*)d_ws;
  size_t o = 0;
  float* dbuf  = f + o; o += (size_t)NMOL*4096;
  float* sig   = f + o; o += NFLAT;
  float* invj  = f + o; o += NFLAT;
  float* pmf   = f + o; o += NFLAT;
  float* q     = f + o; o += NFLAT;
  float* chi   = f + o; o += NFLAT;
  _Float16* feat = (_Float16*)(f + o); o += (size_t)NFLAT*FK/2;
  _Float16* h0h  = (_Float16*)(f + o); o += (size_t)MPAD*D0/2;
  _Float16* h1h  = (_Float16*)(f + o); o += (size_t)MPAD*D1/2;
  _Float16* h2h  = h0h;   // layer2 writes over h0 (already consumed)
  // Wt[i]: [4][KT*4][N][8] fp16
  const int KT_[3] = {14, 8, 6};
  const int N_[3]  = {D0, D1, D2};
  _Float16* wt[6];
  for (int i=0;i<6;i++){
    wt[i] = (_Float16*)(f + o);
    o += (size_t)4*KT_[i%3]*N_[i%3]*32/2;
  }
  int* meta    = (int*)(f + o); o += 64;
  int* idxarr  = (int*)(f + o); o += MPAD;
  int* blkhist = (int*)(f + o); o += NMOL*4;
  int* blkoff  = (int*)(f + o); o += NMOL*4;

  // ---- one-time prep (per launch) ----
  cvt_aev_kernel<<<dim3(NFLAT/4), 256, 0, stream>>>(aev, feat);
  for (int li=0; li<3; ++li){
    int K = (li==0) ? 418 : (li==1 ? D0 : D1);
    int N = N_[li], KT = KT_[li];
    wtrans_kernel<<<dim3((KT*4*N+255)/256, 4, 2), 256, 0, stream>>>(
        cW[li], aW[li], wt[li], wt[3+li], K, N, KT);
  }
  prep_kernel<<<dim3(NMOL), 256, 0, stream>>>(species, coord, dbuf, sig, invj, pmf, blkhist);
  plan_kernel<<<dim3(1), 64, 0, stream>>>(blkhist, meta, blkoff);
  scatter_kernel<<<dim3(NMOL), 64, 0, stream>>>(species, blkoff, idxarr);

  for (int pass=0; pass<3; ++pass){
    int wb = (pass<2) ? 0 : 3;
    const float* const* Bp = (pass<2) ? cB : aB;
    int kt0 = (pass==0) ? 12 : 14;   // pass-0: extra features exactly zero -> skip 2 k-steps
    gemm_gll<1,8,14><<<dim3(516,2), 256, 0, stream>>>(nullptr, feat, idxarr, meta,
                                                      wt[wb+0], Bp[0], h0h, D0, kt0, 1);
    gemm_gll<0,6, 8><<<dim3(516,2), 256, 0, stream>>>(h0h, nullptr, idxarr, meta,
                                                      wt[wb+1], Bp[1], h1h, D1, 8, 1);
    gemm_gll<0,5, 6><<<dim3(516,2), 256, 0, stream>>>(h1h, nullptr, idxarr, meta,
                                                      wt[wb+2], Bp[2], h2h, D2, 6, 1);
    layer3_kernel<<<dim3(MPAD/4), 256, 0, stream>>>(h2h, idxarr, meta, (pass<2)?cW[3]:aW[3],
                                                    (pass<2)?cB[3]:aB[3], chi);
    if (pass < 2)
      iter_kernel<<<dim3(NMOL), 512, 0, stream>>>(chi, invj, pmf, netq, dbuf, sig, q, feat);
  }
  final_kernel<<<dim3(NMOL), 64, 0, stream>>>(dbuf, q, pmf, chi, species, (float*)d_out);
}

// Round 14
// 273.306 us; speedup vs baseline: 2.1683x; 1.1282x over previous
//
#include <hip/hip_runtime.h>
#include <math.h>

#define NMOL 512
#define NATOM 64
#define NFLAT (NMOL*NATOM)
#define AEVL 384
#define FK 448           // fp16 feature row: 384 aev | 32 qraev | q | esp | 30 pad(0)
#define D0 256
#define D1 192
#define D2 160
#define MPAD 33024

typedef _Float16 h8 __attribute__((ext_vector_type(8)));
typedef float    f4 __attribute__((ext_vector_type(4)));

__constant__ float c_sigma[8] = {0.5515909f,1.8886297f,1.3225029f,1.2316629f,
                                 2.1884933f,1.7750372f,1.3677907f,1.3820058f};

__device__ __forceinline__ float wsum(float v){
  #pragma unroll
  for (int o=1;o<64;o<<=1) v += __shfl_xor(v,o);
  return v;
}

// direct global->LDS copy, 16B per lane; lds base must be wave-uniform
__device__ __forceinline__ void gll16(const _Float16* g, _Float16* l){
  __builtin_amdgcn_global_load_lds(
    (const __attribute__((address_space(1))) void*)g,
    (__attribute__((address_space(3))) void*)l, 16, 0, 0);
}

// ---------------- AEV -> fp16 feature rows (tail 384..447 zeroed) ----------------
__global__ void cvt_aev_kernel(const float* __restrict__ aev, _Float16* __restrict__ feat){
  int atom = blockIdx.x*4 + (threadIdx.x>>6);
  int c = threadIdx.x & 63;
  if (c >= 56) return;
  int k8 = c*8;
  h8 o;
  if (k8 < AEVL){
    const f4* s = reinterpret_cast<const f4*>(aev + (size_t)atom*AEVL + k8);
    f4 a = s[0], b = s[1];
    o[0]=(_Float16)a[0]; o[1]=(_Float16)a[1]; o[2]=(_Float16)a[2]; o[3]=(_Float16)a[3];
    o[4]=(_Float16)b[0]; o[5]=(_Float16)b[1]; o[6]=(_Float16)b[2]; o[7]=(_Float16)b[3];
  } else {
    #pragma unroll
    for (int i=0;i<8;i++) o[i] = (_Float16)0.f;
  }
  *reinterpret_cast<h8*>(feat + (size_t)atom*FK + k8) = o;
}

// ---- W [4][K][N] f32 -> Wt [4][KT][4part][N][8] fp16 (linear-stageable, zero-padded) ----
__global__ void wtrans_kernel(const float* __restrict__ Wc, const float* __restrict__ Wa,
                              _Float16* __restrict__ WtC, _Float16* __restrict__ WtA,
                              int K, int N, int KT){
  int u = blockIdx.x*256 + threadIdx.x;
  if (u >= KT*4*N) return;
  int col = u % N;
  int pk  = u / N;           // kt*4+part
  int part = pk & 3, kt = pk >> 2;
  int s = blockIdx.y;
  const float* W = (blockIdx.z == 0) ? Wc : Wa;
  _Float16* Wt   = (blockIdx.z == 0) ? WtC : WtA;
  h8 o;
  #pragma unroll
  for (int e=0;e<8;e++){
    int gk = kt*32 + part*8 + e;
    float v = (gk < K) ? W[((size_t)s*K + gk)*N + col] : 0.f;
    o[e] = (_Float16)v;
  }
  *reinterpret_cast<h8*>(Wt + ((size_t)s*KT*4 + pk)*N*8 + (size_t)col*8) = o;
}

// ---------------- distances + per-atom species data + per-molecule histogram ----------------
__global__ void prep_kernel(const int* __restrict__ species,
                            const float* __restrict__ coord,
                            float* __restrict__ dbuf, float* __restrict__ sig,
                            float* __restrict__ invj, float* __restrict__ pmf,
                            int* __restrict__ blkhist){
  int m = blockIdx.x, t = threadIdx.x;
  __shared__ float c[192];
  if (t < 192) c[t] = coord[m*192 + t];
  __syncthreads();
  #pragma unroll
  for (int k=0;k<16;k++){
    int p = t + 256*k;
    int i = p >> 6, j = p & 63;
    float dx=c[i*3]-c[j*3], dy=c[i*3+1]-c[j*3+1], dz=c[i*3+2]-c[j*3+2];
    dbuf[m*4096 + p] = sqrtf(dx*dx+dy*dy+dz*dz + 1e-16f) / 0.529177249f;
  }
  if (t < 64){
    int g = m*64+t;
    int s = species[g];
    float sg = c_sigma[s < 0 ? 7 : s];
    sig[g]  = sg;
    invj[g] = 1.7724539f * sg;   // sqrt(pi) fp32
    pmf[g]  = (s>=0) ? 1.f : 0.f;
    #pragma unroll
    for (int sp=0;sp<4;sp++){
      unsigned long long mask = __ballot(s==sp);
      if (t==0) blkhist[m*4+sp] = __popcll(mask);
    }
  }
}

// ---------------- plan: 64-aligned bases; LDS-resident scan ----------------
// meta: [0..3] counts, [4..8] base(64-aligned, [8]=total rows), [9..13] tile_base ([13]=total tiles)
__global__ void plan_kernel(const int* __restrict__ blkhist, int* __restrict__ meta,
                            int* __restrict__ blkoff){
  __shared__ int h[NMOL*4];
  __shared__ int tot[4], base[4];
  int t = threadIdx.x;
  for (int j=t; j<NMOL*4; j+=256) h[j] = blkhist[j];
  __syncthreads();
  if (t < 4){
    int sum = 0;
    for (int m=0;m<NMOL;m++) sum += h[m*4+t];
    tot[t] = sum;
  }
  __syncthreads();
  if (t == 0){
    int b=0, tb=0;
    meta[4]=0; meta[9]=0;
    for (int s=0;s<4;s++){
      meta[s] = tot[s];
      base[s] = b;
      int tiles = (tot[s]+63)>>6;
      b  += tiles<<6;  tb += tiles;
      meta[5+s]  = b;  meta[10+s] = tb;
    }
  }
  __syncthreads();
  if (t < 4){
    int run = base[t];
    for (int m=0;m<NMOL;m++){ int v = h[m*4+t]; h[m*4+t] = run; run += v; }
  }
  __syncthreads();
  for (int j=t; j<NMOL*4; j+=256) blkoff[j] = h[j];
}

// ---------------- deterministic atomic-free scatter ----------------
__global__ void scatter_kernel(const int* __restrict__ species,
                               const int* __restrict__ blkoff,
                               int* __restrict__ idxarr){
  int m = blockIdx.x, a = threadIdx.x, g = m*64+a;
  int s = species[g];
  unsigned long long below = (1ull<<a) - 1ull;
  #pragma unroll
  for (int sp=0;sp<4;sp++){
    unsigned long long mask = __ballot(s==sp);
    if (s==sp){
      int rank = __popcll(mask & below);
      idxarr[blkoff[m*4+sp] + rank] = g;
    }
  }
}

// ======== m97-style fp16 MFMA GEMM: A+B staged via global_load_lds, dbuf, 1 barrier/k-step ========
// Block: 64 rows x COLS cols (COLS=NCB*16), 4 waves; wave w: rows [w*16,+16) x all COLS.
// FUSEL3: apply celu and fold the [COLS]-wide W3 dot in-register -> write scalar chi (no C write).
template<int GATHER, int NCB, int KTW, int FUSEL3>
__launch_bounds__(256)
__global__ void gemm_gll(const _Float16* __restrict__ Ah,    // [rows][KTW*32]  (GATHER=0)
                         const _Float16* __restrict__ feat,  // [NFLAT][FK]     (GATHER=1)
                         const int* __restrict__ idxarr,
                         const int* __restrict__ meta,
                         const _Float16* __restrict__ Wt,    // [4][KTW*4][N][8]
                         const float* __restrict__ Ball,     // [4][N]
                         _Float16* __restrict__ C,           // [rows][N] (FUSEL3=0)
                         const float* __restrict__ W3a,      // [4][COLS]  (FUSEL3=1)
                         const float* __restrict__ b3a,      // [4]
                         float* __restrict__ outv,           // [NFLAT]    (FUSEL3=1)
                         int N, int ktrun, int act){
  constexpr int COLS = NCB*16;
  constexpr int NB16 = COLS/16;          // 1KB-instructions per B k-tile
  int t = blockIdx.x;
  if (t >= meta[13]) return;
  int s = 0;
  while (s < 3 && t >= meta[10+s]) s++;
  int trow = t - meta[9+s];
  int row0 = meta[4+s] + (trow<<6);
  int mrem = meta[s] - (trow<<6); if (mrem > 64) mrem = 64;
  int c0 = blockIdx.y * COLS;

  __shared__ __align__(16) _Float16 Ab[2][2048];        // [part][row][8]
  __shared__ __align__(16) _Float16 Bb[2][COLS*32];     // [part][col][8]

  int tid = threadIdx.x;
  int w = tid>>6, l = tid&63, lr16 = l&15, lg = l>>4;

  // per-lane A source row (lane = row within tile)
  int arow = row0 + l;
  int amax = row0 + mrem - 1;
  if (arow > amax) arow = amax;
  const _Float16* asrc;
  if (GATHER) asrc = feat + (size_t)idxarr[arow]*FK;
  else        asrc = Ah + (size_t)arow*(KTW*32);

  const _Float16* Wbase = Wt + (size_t)s*KTW*4*N*8 + (size_t)c0*8;

  // stage k-step kt into buffer buf
  auto STAGE = [&](int buf, int kt){
    gll16(asrc + kt*32 + w*8, &Ab[buf][w*512]);
    for (int j=w; j<NB16; j+=4){
      int u = j*64 + l;
      int part = u / COLS, col = u - part*COLS;
      gll16(Wbase + ((size_t)(kt*4+part)*N + col)*8, &Bb[buf][j*512]);
    }
  };

  f4 acc[NCB];
  #pragma unroll
  for (int c=0;c<NCB;c++){ acc[c][0]=0.f; acc[c][1]=0.f; acc[c][2]=0.f; acc[c][3]=0.f; }

  STAGE(0, 0);
  __syncthreads();
  int cur = 0;
  for (int kt=0; kt<ktrun; ++kt){
    if (kt+1 < ktrun) STAGE(cur^1, kt+1);
    h8 aF = *reinterpret_cast<const h8*>(&Ab[cur][lg*512 + (w*16+lr16)*8]);
    #pragma unroll
    for (int c=0;c<NCB;c++){
      h8 bF = *reinterpret_cast<const h8*>(&Bb[cur][lg*COLS*8 + (c*16+lr16)*8]);
      acc[c] = __builtin_amdgcn_mfma_f32_16x16x32_f16(aF, bF, acc[c], 0, 0, 0);
    }
    if (kt+1 < ktrun){
      __syncthreads();
      cur ^= 1;
    }
  }

  // epilogue: C/D layout col=lane&15, row=(lane>>4)*4+reg (HW-verified)
  const float* bias = Ball + s*N;
  if (FUSEL3){
    // celu + W3 dot entirely in-register; 16-lane (lr16) reduce covers all COLS cols
    const float* w3 = W3a + s*COLS;
    float vrow[4] = {0.f,0.f,0.f,0.f};
    #pragma unroll
    for (int c=0;c<NCB;c++){
      int col = c*16 + lr16;
      float bsv = bias[col];
      float wv  = w3[col];
      #pragma unroll
      for (int rr=0;rr<4;rr++){
        float vv = acc[c][rr] + bsv;
        vv = vv > 0.f ? vv : 0.1f*expm1f(vv*10.f);
        vrow[rr] += vv * wv;
      }
    }
    float b3v = b3a[s];
    #pragma unroll
    for (int rr=0;rr<4;rr++){
      float v = vrow[rr];
      #pragma unroll
      for (int o=1;o<16;o<<=1) v += __shfl_xor(v, o);
      int lrow = w*16 + lg*4 + rr;
      if (lr16 == 0 && lrow < mrem)
        outv[idxarr[row0+lrow]] = v + b3v;
    }
  } else {
    #pragma unroll
    for (int c=0;c<NCB;c++){
      int col = c0 + c*16 + lr16;
      float bsv = bias[col];
      #pragma unroll
      for (int rr=0;rr<4;rr++){
        int lrow = w*16 + lg*4 + rr;
        if (lrow >= mrem) continue;
        float vv = acc[c][rr] + bsv;
        if (act) vv = vv > 0.f ? vv : 0.1f*expm1f(vv*10.f);
        C[(size_t)(row0+lrow)*N + col] = (_Float16)vv;
      }
    }
  }
}

// ---- fused charge iteration (512 thr): qupdate + esp(8-way) + qraev(recurrence, 2x4 split) ----
__global__ void iter_kernel(const float* __restrict__ chi, const float* __restrict__ invj,
                            const float* __restrict__ pmf, const float* __restrict__ netq,
                            const float* __restrict__ dbuf, const float* __restrict__ sig,
                            float* __restrict__ q, _Float16* __restrict__ feat){
  int m = blockIdx.x, tid = threadIdx.x;
  int i = tid & 63, w = tid >> 6;   // w in 0..7
  __shared__ float qs[64], pms[64], sg2[64];
  __shared__ float esp8[8][64];
  __shared__ float qr[8][64][8];
  if (tid < 64){
    int g = m*64 + i;
    float pm = pmf[g], ij = invj[g];
    float c = pm > 0.f ? chi[g] : 0.f;
    float num = wsum(c*ij);
    float den = wsum(ij*pm);
    float corr = (netq[m] + num) / den;
    float qa = -ij*(c - corr)*pm;
    q[g] = qa;
    feat[(size_t)g*FK + 416] = (_Float16)qa;
    qs[i] = qa; pms[i] = pm;
    float s0 = sig[g]; sg2[i] = s0*s0;
  }
  __syncthreads();
  const float* dr = dbuf + (size_t)m*4096;
  {
    float si2 = sg2[i];
    float acc = 0.f;
    #pragma unroll
    for (int jj=0;jj<8;jj++){
      int j = w*8 + jj;
      if (j==i) continue;
      float d = dr[j*64 + i];
      float ss = fmaxf(si2 + sg2[j], 1e-8f);
      acc += qs[j]*pms[j]*erff(d/sqrtf(2.f*ss))/d;
    }
    esp8[w][i] = acc;
  }
  {
    const float STEP = 0.264516129f;     // 8.2/31
    const float C2 = 0.7558781f;         // exp(-4*STEP^2)
    const float C1 = 0.5713518f;         // exp(-8*STEP^2)
    int jh = w>>2, bg = w&3;
    float rbase = 0.8f + (bg*8)*STEP;
    float pmi = pms[i];
    float acc[8] = {0.f,0.f,0.f,0.f,0.f,0.f,0.f,0.f};
    for (int jj=0;jj<32;jj++){
      int j = jh*32 + jj;
      if (j==i) continue;
      float d = dr[j*64+i];
      if (d < 10.f){
        float wq = 0.25f*(0.5f*__cosf(0.31415927f*d)+0.5f)*qs[j]*pms[j]*pmi;
        if (wq != 0.f){
          float t0 = d - rbase;
          float fv = __expf(-4.f*t0*t0);
          float gv = __expf(2.116129f*t0)*C2;
          #pragma unroll
          for (int r=0;r<8;r++){ acc[r] += wq*fv; fv *= gv; gv *= C1; }
        }
      }
    }
    #pragma unroll
    for (int r=0;r<8;r++) qr[w][i][r] = acc[r];
  }
  __syncthreads();
  if (tid < 64){
    int g = m*64+i;
    float e = 0.f;
    #pragma unroll
    for (int k=0;k<8;k++) e += esp8[k][i];
    feat[(size_t)g*FK + 417] = (_Float16)(e * pms[i]);
  }
  if (tid < 256){
    int ii = tid & 63, bg = tid >> 6;
    h8 o;
    #pragma unroll
    for (int r=0;r<8;r++) o[r] = (_Float16)(qr[bg][ii][r] + qr[bg+4][ii][r]);
    *reinterpret_cast<h8*>(feat + (size_t)(m*64+ii)*FK + 384 + bg*8) = o;
  }
}

// ---------------- screened Coulomb + energy + outputs ----------------
__global__ void final_kernel(const float* __restrict__ dbuf, const float* __restrict__ q,
                             const float* __restrict__ pmf, const float* __restrict__ ae,
                             const int* __restrict__ species, float* __restrict__ out){
  int m = blockIdx.x, a = threadIdx.x, g = m*64+a;
  __shared__ float qs[64], pms[64];
  qs[a]=q[g]; pms[a]=pmf[g];
  __syncthreads();
  float acc=0.f;
  const float* dr = dbuf + (size_t)m*4096;
  for (int b=0;b<64;b++){
    if (b==a) continue;
    float d = dr[b*64+a];
    float sgm = 1.f/(1.f+__expf(-(d-2.2f)*8.5f));
    acc += qs[b]*pms[b]*sgm/d;
  }
  float e = 0.5f*qs[a]*pms[a]*acc;
  float aea = pms[a]>0.f ? ae[g] : 0.f;
  float tot = wsum(e + aea);
  if (a == 0) out[NFLAT + m] = tot;
  out[g] = (float)species[g];
  out[NFLAT + NMOL + g] = qs[a];
}

extern "C" void kernel_launch(void* const* d_in, const int* in_sizes, int n_in,
                              void* d_out, int out_size, void* d_ws, size_t ws_size,
                              hipStream_t stream){
  const int*   species = (const int*)d_in[0];
  const float* coord   = (const float*)d_in[1];
  const float* netq    = (const float*)d_in[2];
  const float* aev     = (const float*)d_in[3];
  const float* cW[4] = {(const float*)d_in[4],(const float*)d_in[6],(const float*)d_in[8],(const float*)d_in[10]};
  const float* cB[4] = {(const float*)d_in[5],(const float*)d_in[7],(const float*)d_in[9],(const float*)d_in[11]};
  const float* aW[4] = {(const float*)d_in[12],(const float*)d_in[14],(const float*)d_in[16],(const float*)d_in[18]};
  const float* aB[4] = {(const float*)d_in[13],(const float*)d_in[15],(const float*)d_in[17],(const float*)d_in[19]};

  // workspace layout (float units; fp16 regions counted as elems/2, all 16B-aligned)
  float* f = (float*)d_ws;
  size_t o = 0;
  float* dbuf  = f + o; o += (size_t)NMOL*4096;
  float* sig   = f + o; o += NFLAT;
  float* invj  = f + o; o += NFLAT;
  float* pmf   = f + o; o += NFLAT;
  float* q     = f + o; o += NFLAT;
  float* chi   = f + o; o += NFLAT;
  _Float16* feat = (_Float16*)(f + o); o += (size_t)NFLAT*FK/2;
  _Float16* h0h  = (_Float16*)(f + o); o += (size_t)MPAD*D0/2;
  _Float16* h1h  = (_Float16*)(f + o); o += (size_t)MPAD*D1/2;
  // Wt[i]: [4][KT*4][N][8] fp16
  const int KT_[3] = {14, 8, 6};
  const int N_[3]  = {D0, D1, D2};
  _Float16* wt[6];
  for (int i=0;i<6;i++){
    wt[i] = (_Float16*)(f + o);
    o += (size_t)4*KT_[i%3]*N_[i%3]*32/2;
  }
  int* meta    = (int*)(f + o); o += 64;
  int* idxarr  = (int*)(f + o); o += MPAD;
  int* blkhist = (int*)(f + o); o += NMOL*4;
  int* blkoff  = (int*)(f + o); o += NMOL*4;

  // ---- one-time prep (per launch) ----
  cvt_aev_kernel<<<dim3(NFLAT/4), 256, 0, stream>>>(aev, feat);
  for (int li=0; li<3; ++li){
    int K = (li==0) ? 418 : (li==1 ? D0 : D1);
    int N = N_[li], KT = KT_[li];
    wtrans_kernel<<<dim3((KT*4*N+255)/256, 4, 2), 256, 0, stream>>>(
        cW[li], aW[li], wt[li], wt[3+li], K, N, KT);
  }
  prep_kernel<<<dim3(NMOL), 256, 0, stream>>>(species, coord, dbuf, sig, invj, pmf, blkhist);
  plan_kernel<<<dim3(1), 256, 0, stream>>>(blkhist, meta, blkoff);
  scatter_kernel<<<dim3(NMOL), 64, 0, stream>>>(species, blkoff, idxarr);

  for (int pass=0; pass<3; ++pass){
    int wb = (pass<2) ? 0 : 3;
    const float* const* Bp = (pass<2) ? cB : aB;
    const float* W3 = (pass<2) ? cW[3] : aW[3];
    const float* b3 = (pass<2) ? cB[3] : aB[3];
    int kt0 = (pass==0) ? 12 : 14;   // pass-0: extra features exactly zero -> skip 2 k-steps
    gemm_gll<1,8,14,0><<<dim3(516,2), 256, 0, stream>>>(nullptr, feat, idxarr, meta,
                                                        wt[wb+0], Bp[0], h0h,
                                                        nullptr, nullptr, nullptr, D0, kt0, 1);
    gemm_gll<0,6,8,0><<<dim3(516,2), 256, 0, stream>>>(h0h, nullptr, idxarr, meta,
                                                       wt[wb+1], Bp[1], h1h,
                                                       nullptr, nullptr, nullptr, D1, 8, 1);
    gemm_gll<0,10,6,1><<<dim3(516,1), 256, 0, stream>>>(h1h, nullptr, idxarr, meta,
                                                        wt[wb+2], Bp[2], nullptr,
                                                        W3, b3, chi, D2, 6, 1);
    if (pass < 2)
      iter_kernel<<<dim3(NMOL), 512, 0, stream>>>(chi, invj, pmf, netq, dbuf, sig, q, feat);
  }
  final_kernel<<<dim3(NMOL), 64, 0, stream>>>(dbuf, q, pmf, chi, species, (float*)d_out);
}